// Round 2
// baseline (439.124 us; speedup 1.0000x reference)
//
#include <hip/hip_runtime.h>
#include <hip/hip_bf16.h>

#define H_DIM  1024
#define RANK_  4
#define BATCH_ 128
#define TSTEPS 256
#define M_DIM  (BATCH_ * TSTEPS)   // 32768

typedef __bf16 bf16x8 __attribute__((ext_vector_type(8)));
typedef float  floatx4 __attribute__((ext_vector_type(4)));
typedef unsigned short ushortx8 __attribute__((ext_vector_type(8)));

// RNE float -> bf16 (branchless; inputs are finite)
__device__ __forceinline__ unsigned short f2bf(float f) {
    unsigned u = __float_as_uint(f);
    u += 0x7FFFu + ((u >> 16) & 1u);
    return (unsigned short)(u >> 16);
}

// ---------------- conversion kernels ----------------

__global__ __launch_bounds__(256) void cvt_x_kernel(const float* __restrict__ x,
                                                    unsigned short* __restrict__ xb) {
    size_t i = ((size_t)blockIdx.x * 256 + threadIdx.x) * 8;
    float4 v0 = *(const float4*)(x + i);
    float4 v1 = *(const float4*)(x + i + 4);
    ushortx8 o;
    o[0] = f2bf(v0.x); o[1] = f2bf(v0.y); o[2] = f2bf(v0.z); o[3] = f2bf(v0.w);
    o[4] = f2bf(v1.x); o[5] = f2bf(v1.y); o[6] = f2bf(v1.z); o[7] = f2bf(v1.w);
    *(ushortx8*)(xb + i) = o;
}

// Bt[n][k] = bf16(B[k][n])
__global__ __launch_bounds__(256) void cvt_bt_kernel(const float* __restrict__ B,
                                                     unsigned short* __restrict__ Bt) {
    __shared__ float tl[32][33];
    int tx = threadIdx.x & 31, ty = threadIdx.x >> 5;   // ty in 0..7
    int k0 = blockIdx.y * 32, n0 = blockIdx.x * 32;
#pragma unroll
    for (int j = 0; j < 4; ++j)
        tl[ty + 8 * j][tx] = B[(size_t)(k0 + ty + 8 * j) * H_DIM + n0 + tx];
    __syncthreads();
#pragma unroll
    for (int j = 0; j < 4; ++j)
        Bt[(size_t)(n0 + ty + 8 * j) * H_DIM + k0 + tx] = f2bf(tl[tx][ty + 8 * j]);
}

// ---------------- bf16 MFMA GEMM, 256x256 8-phase schedule ----------------
// (unchanged from previous round: 147us -> off the top-5)

#define BM 256
#define BN 256
#define BKK 64
#define KTILES (H_DIM / BKK)   // 16

#define GLD(srcptr, dstptr)                                          \
    __builtin_amdgcn_global_load_lds(                                \
        (const __attribute__((address_space(1))) void*)(srcptr),     \
        (__attribute__((address_space(3))) void*)(dstptr), 16, 0, 0)

#define STAGE_A(buf, hf, kt) do {                                                     \
    GLD(aS0 + (size_t)(hf) * (128 * H_DIM) + (kt) * BKK, &lds[buf][0][hf][dst0]);     \
    GLD(aS1 + (size_t)(hf) * (128 * H_DIM) + (kt) * BKK, &lds[buf][0][hf][dst1]);     \
} while (0)

#define STAGE_B(buf, hf, kt) do {                                                     \
    GLD(bS0 + (size_t)(hf) * (128 * H_DIM) + (kt) * BKK, &lds[buf][1][hf][dst0]);     \
    GLD(bS1 + (size_t)(hf) * (128 * H_DIM) + (kt) * BKK, &lds[buf][1][hf][dst1]);     \
} while (0)

#define MFMA_PHASE(q)                                                                                         \
    _Pragma("unroll")                                                                                         \
    for (int fc = 0; fc < 4; ++fc) {                                                                          \
        acc[2*(q)][fc]   = __builtin_amdgcn_mfma_f32_16x16x32_bf16(a00, bfr[fc][0], acc[2*(q)][fc], 0, 0, 0);   \
        acc[2*(q)][fc]   = __builtin_amdgcn_mfma_f32_16x16x32_bf16(a01, bfr[fc][1], acc[2*(q)][fc], 0, 0, 0);   \
        acc[2*(q)+1][fc] = __builtin_amdgcn_mfma_f32_16x16x32_bf16(a10, bfr[fc][0], acc[2*(q)+1][fc], 0, 0, 0); \
        acc[2*(q)+1][fc] = __builtin_amdgcn_mfma_f32_16x16x32_bf16(a11, bfr[fc][1], acc[2*(q)+1][fc], 0, 0, 0); \
    }

#define PHASE(q, STAGE_STMT, TAIL_STMT) {                                      \
        bf16x8 a00 = *(const bf16x8*)(Ah + (2*(q))     * 1024 + aRow + cs0);   \
        bf16x8 a01 = *(const bf16x8*)(Ah + (2*(q))     * 1024 + aRow + cs1);   \
        bf16x8 a10 = *(const bf16x8*)(Ah + (2*(q) + 1) * 1024 + aRow + cs0);   \
        bf16x8 a11 = *(const bf16x8*)(Ah + (2*(q) + 1) * 1024 + aRow + cs1);   \
        STAGE_STMT;                                                            \
        __builtin_amdgcn_s_barrier();                                          \
        asm volatile("s_waitcnt lgkmcnt(0)" ::: "memory");                     \
        __builtin_amdgcn_s_setprio(1);                                         \
        MFMA_PHASE(q);                                                         \
        __builtin_amdgcn_s_setprio(0);                                         \
        TAIL_STMT;                                                             \
        __builtin_amdgcn_s_barrier();                                          \
    }

__global__ __launch_bounds__(512, 2) void gemm_bf16_256(const unsigned short* __restrict__ A,
                                                        const unsigned short* __restrict__ Bt,
                                                        float* __restrict__ C) {
    __shared__ unsigned short lds[2][2][2][8192];   // [dbuf][A=0/B=1][half][128*64] = 128KB

    const int tid = threadIdx.x;
    const int l   = tid & 63;
    const int w   = tid >> 6;      // 0..7
    const int wr  = w >> 2;        // 0..1  M-side (128 rows)
    const int wc  = w & 3;         // 0..3  N-side (64 cols)

    const int bid = blockIdx.x;
    const int lt  = (bid & 7) * 64 + (bid >> 3);
    const int m0  = (lt >> 2) * BM;
    const int n0  = (lt & 3)  * BN;

    const int p0row = (w * 2 + 0) * 8 + (l >> 3);
    const int p1row = (w * 2 + 1) * 8 + (l >> 3);
    const int gcol  = ((l & 7) ^ (l >> 3)) * 8;
    const int dst0  = (w * 2 + 0) * 512;
    const int dst1  = (w * 2 + 1) * 512;
    const unsigned short* aS0 = A  + (size_t)(m0 + p0row) * H_DIM + gcol;
    const unsigned short* aS1 = A  + (size_t)(m0 + p1row) * H_DIM + gcol;
    const unsigned short* bS0 = Bt + (size_t)(n0 + p0row) * H_DIM + gcol;
    const unsigned short* bS1 = Bt + (size_t)(n0 + p1row) * H_DIM + gcol;

    const int aRow = (l & 15) * 64;
    const int cs0  = (((l >> 4) + 0) ^ (l & 7)) * 8;
    const int cs1  = (((l >> 4) + 4) ^ (l & 7)) * 8;

    floatx4 acc[8][4];
#pragma unroll
    for (int i = 0; i < 8; ++i)
#pragma unroll
        for (int j = 0; j < 4; ++j) acc[i][j] = (floatx4){0.f, 0.f, 0.f, 0.f};

    STAGE_B(0, 0, 0); STAGE_B(0, 1, 0); STAGE_A(0, 0, 0); STAGE_A(0, 1, 0);
    STAGE_B(1, 0, 1); STAGE_B(1, 1, 1); STAGE_A(1, 0, 1);
    asm volatile("s_waitcnt vmcnt(6)" ::: "memory");   // oldest 4 halves (t0) done
    __builtin_amdgcn_s_barrier();

    for (int kt = 0; kt < KTILES; ++kt) {
        const int buf = kt & 1;
        const unsigned short* Ah = &lds[buf][0][wr][0];
        const unsigned short* Bh = &lds[buf][1][wc >> 1][(wc & 1) * 4096];
        bf16x8 bfr[4][2];

        {
            bf16x8 a00 = *(const bf16x8*)(Ah + 0 * 1024 + aRow + cs0);
            bf16x8 a01 = *(const bf16x8*)(Ah + 0 * 1024 + aRow + cs1);
            bf16x8 a10 = *(const bf16x8*)(Ah + 1 * 1024 + aRow + cs0);
            bf16x8 a11 = *(const bf16x8*)(Ah + 1 * 1024 + aRow + cs1);
#pragma unroll
            for (int fc = 0; fc < 4; ++fc) {
                bfr[fc][0] = *(const bf16x8*)(Bh + fc * 1024 + aRow + cs0);
                bfr[fc][1] = *(const bf16x8*)(Bh + fc * 1024 + aRow + cs1);
            }
            if (kt + 1 < KTILES) STAGE_A(buf ^ 1, 1, kt + 1);
            __builtin_amdgcn_s_barrier();
            asm volatile("s_waitcnt lgkmcnt(0)" ::: "memory");
            __builtin_amdgcn_s_setprio(1);
            MFMA_PHASE(0);
            __builtin_amdgcn_s_setprio(0);
            __builtin_amdgcn_s_barrier();
        }
        PHASE(1, if (kt + 2 < KTILES) STAGE_B(buf, 0, kt + 2), );
        PHASE(2, if (kt + 2 < KTILES) STAGE_B(buf, 1, kt + 2), );
        PHASE(3, if (kt + 2 < KTILES) STAGE_A(buf, 0, kt + 2),
              if (kt < KTILES - 2) { asm volatile("s_waitcnt vmcnt(6)" ::: "memory"); }
              else if (kt == KTILES - 2) { asm volatile("s_waitcnt vmcnt(0)" ::: "memory"); });
    }

    const int cr = (l >> 4) * 4;
    const int cc = l & 15;
#pragma unroll
    for (int fr = 0; fr < 8; ++fr)
#pragma unroll
        for (int fc = 0; fc < 4; ++fc) {
            size_t base = (size_t)(m0 + wr * 128 + fr * 16 + cr) * H_DIM
                        + (n0 + wc * 64 + fc * 16 + cc);
#pragma unroll
            for (int r = 0; r < 4; ++r)
                C[base + (size_t)r * H_DIM] = acc[fr][fc][r];
        }
}

// ---------------- fp32 fallback GEMM (only if ws too small) ----------------
__global__ __launch_bounds__(256) void gemm_fp32_fallback(const float* __restrict__ A,
                                                          const float* __restrict__ B,
                                                          float* __restrict__ C) {
    __shared__ float As[64][20];
    __shared__ float Bs[16][68];
    const int tid = threadIdx.x;
    const int bm = blockIdx.x >> 4, bn = blockIdx.x & 15;
    const int m0 = bm * 64, n0 = bn * 64;
    const int tx = (tid & 15) * 4, ty = (tid >> 4) * 4;
    float acc[4][4];
#pragma unroll
    for (int i = 0; i < 4; ++i)
#pragma unroll
        for (int j = 0; j < 4; ++j) acc[i][j] = 0.f;

    for (int kk = 0; kk < H_DIM; kk += 16) {
        float4 av = *(const float4*)(A + (size_t)(m0 + (tid >> 2)) * H_DIM + kk + (tid & 3) * 4);
        float4 bv = *(const float4*)(B + (size_t)(kk + (tid >> 4)) * H_DIM + n0 + (tid & 15) * 4);
        __syncthreads();
        *(float4*)&As[tid >> 2][(tid & 3) * 4] = av;
        *(float4*)&Bs[tid >> 4][(tid & 15) * 4] = bv;
        __syncthreads();
#pragma unroll
        for (int k = 0; k < 16; ++k) {
            float a_[4], b_[4];
#pragma unroll
            for (int i = 0; i < 4; ++i) a_[i] = As[ty + i][k];
#pragma unroll
            for (int j = 0; j < 4; ++j) b_[j] = Bs[k][tx + j];
#pragma unroll
            for (int i = 0; i < 4; ++i)
#pragma unroll
                for (int j = 0; j < 4; ++j) acc[i][j] += a_[i] * b_[j];
        }
    }
#pragma unroll
    for (int i = 0; i < 4; ++i)
#pragma unroll
        for (int j = 0; j < 4; ++j)
            C[(size_t)(m0 + ty + i) * H_DIM + n0 + tx + j] = acc[i][j];
}

// ---------------- sequential scan (in-place on d_out) ----------------
// 8 waves x 2 el/lane (was 4 waves x 4): halves the per-wave VALU issue on the
// serial critical path (update/tanh, pr partials, L-combine) while the fixed
// cross-wave exchange cost (ds roundtrip + barrier) is unchanged. The a = d*h+u
// FMAs are hoisted BEFORE the barrier (independent of r) to fill exchange latency.

__device__ __forceinline__ float tanh_fast(float x) {
    float ax = fabsf(x);
    float e  = __expf(-2.0f * ax);
    float t  = (1.0f - e) * __builtin_amdgcn_rcpf(1.0f + e);
    return copysignf(t, x);
}

// LDS-only barrier: drains lgkmcnt but NOT vmcnt, so global prefetch loads
// and h-stores stay in flight across the barrier.
__device__ __forceinline__ void barrier_lds_only() {
    asm volatile("s_waitcnt lgkmcnt(0)\n\ts_barrier" ::: "memory");
}

// DPP wave64 sum: full sum lands in lane 63 (VALU-rate, no LDS/ds_permute).
template <int CTRL, int RMASK>
__device__ __forceinline__ float dpp_add(float x) {
    int v = __builtin_amdgcn_update_dpp(0, __float_as_int(x), CTRL, RMASK, 0xf, true);
    return x + __int_as_float(v);
}
__device__ __forceinline__ float wave_sum64(float x) {
    x = dpp_add<0x111, 0xf>(x);  // row_shr:1
    x = dpp_add<0x112, 0xf>(x);  // row_shr:2
    x = dpp_add<0x114, 0xf>(x);  // row_shr:4
    x = dpp_add<0x118, 0xf>(x);  // row_shr:8  -> lane15 of each row = row sum
    x = dpp_add<0x142, 0xa>(x);  // row_bcast15 -> rows 1,3
    x = dpp_add<0x143, 0xc>(x);  // row_bcast31 -> rows 2,3; lane 63 = total
    return x;
}

__global__ __launch_bounds__(512) void scan_kernel(const float* __restrict__ h0,
                                                   const float* __restrict__ d,
                                                   const float* __restrict__ Lm,
                                                   const float* __restrict__ Rm,
                                                   float* __restrict__ io) {
    const int b = blockIdx.x, tid = threadIdx.x;
    const int lane = tid & 63, wv = tid >> 6;   // wv in 0..7
    const int e = tid * 2;

    float2 dv2 = *(const float2*)(d + e);
    float dd[2] = {dv2.x, dv2.y};
    float2 hv2 = *(const float2*)(h0 + (size_t)b * H_DIM + e);
    float h[2] = {hv2.x, hv2.y};

    float Lv[2][4], Rv[4][2];
#pragma unroll
    for (int i = 0; i < 2; ++i) {
        float4 t = *(const float4*)(Lm + (size_t)(e + i) * RANK_);   // L[h][j]
        Lv[i][0] = t.x; Lv[i][1] = t.y; Lv[i][2] = t.z; Lv[i][3] = t.w;
    }
#pragma unroll
    for (int j = 0; j < 4; ++j) {
        float2 t = *(const float2*)(Rm + (size_t)j * H_DIM + e);     // R[j][h]
        Rv[j][0] = t.x; Rv[j][1] = t.y;
    }

    float* iob = io + (size_t)b * TSTEPS * H_DIM + e;
    __shared__ float red[2][8][4];   // double-buffered: 1 barrier/step is sound

    // prefetch distance 4, circular buffer, loop unrolled by 4 (static index)
    float2 u[4];
#pragma unroll
    for (int s = 0; s < 4; ++s) u[s] = *(const float2*)(iob + (size_t)s * H_DIM);

    for (int t = 0; t < TSTEPS; t += 4) {
#pragma unroll
        for (int s = 0; s < 4; ++s) {
            const int tt = t + s;
            float pr[4];
#pragma unroll
            for (int j = 0; j < 4; ++j)
                pr[j] = Rv[j][0] * h[0] + Rv[j][1] * h[1];
#pragma unroll
            for (int j = 0; j < 4; ++j) pr[j] = wave_sum64(pr[j]);
            if (lane == 63) {
                float4 w; w.x = pr[0]; w.y = pr[1]; w.z = pr[2]; w.w = pr[3];
                *(float4*)&red[s & 1][wv][0] = w;
            }
            // a = d*h + u is independent of r: compute before the barrier so it
            // overlaps the exchange latency.
            float a0 = fmaf(dd[0], h[0], u[s].x);
            float a1 = fmaf(dd[1], h[1], u[s].y);
            barrier_lds_only();
            float4 r0 = *(const float4*)&red[s & 1][0][0];
            float4 r1 = *(const float4*)&red[s & 1][1][0];
            float4 r2 = *(const float4*)&red[s & 1][2][0];
            float4 r3 = *(const float4*)&red[s & 1][3][0];
            float4 r4 = *(const float4*)&red[s & 1][4][0];
            float4 r5 = *(const float4*)&red[s & 1][5][0];
            float4 r6 = *(const float4*)&red[s & 1][6][0];
            float4 r7 = *(const float4*)&red[s & 1][7][0];
            float ra[4] = {r0.x + r1.x, r0.y + r1.y, r0.z + r1.z, r0.w + r1.w};
            float rb[4] = {r2.x + r3.x, r2.y + r3.y, r2.z + r3.z, r2.w + r3.w};
            float rc[4] = {r4.x + r5.x, r4.y + r5.y, r4.z + r5.z, r4.w + r5.w};
            float rd[4] = {r6.x + r7.x, r6.y + r7.y, r6.z + r7.z, r6.w + r7.w};
            float r[4] = {(ra[0] + rb[0]) + (rc[0] + rd[0]),
                          (ra[1] + rb[1]) + (rc[1] + rd[1]),
                          (ra[2] + rb[2]) + (rc[2] + rd[2]),
                          (ra[3] + rb[3]) + (rc[3] + rd[3])};

            a0 += Lv[0][0] * r[0] + Lv[0][1] * r[1] + Lv[0][2] * r[2] + Lv[0][3] * r[3];
            a1 += Lv[1][0] * r[0] + Lv[1][1] * r[1] + Lv[1][2] * r[2] + Lv[1][3] * r[3];
            h[0] = tanh_fast(a0);
            h[1] = tanh_fast(a1);
            float2 o; o.x = h[0]; o.y = h[1];
            *(float2*)(iob + (size_t)tt * H_DIM) = o;
            if (tt + 4 < TSTEPS) u[s] = *(const float2*)(iob + (size_t)(tt + 4) * H_DIM);
        }
    }
}

// ---------------- launch ----------------

extern "C" void kernel_launch(void* const* d_in, const int* in_sizes, int n_in,
                              void* d_out, int out_size, void* d_ws, size_t ws_size,
                              hipStream_t stream) {
    const float* x  = (const float*)d_in[0];
    const float* h0 = (const float*)d_in[1];
    const float* dd = (const float*)d_in[2];
    const float* L  = (const float*)d_in[3];
    const float* R  = (const float*)d_in[4];
    const float* B  = (const float*)d_in[5];
    float* out = (float*)d_out;

    const size_t need = (size_t)M_DIM * H_DIM * sizeof(unsigned short)
                      + (size_t)H_DIM * H_DIM * sizeof(unsigned short);
    if (ws_size >= need) {
        unsigned short* xb = (unsigned short*)d_ws;
        unsigned short* Bt = xb + (size_t)M_DIM * H_DIM;
        cvt_x_kernel<<<(M_DIM * H_DIM) / (256 * 8), 256, 0, stream>>>(x, xb);
        cvt_bt_kernel<<<dim3(32, 32), 256, 0, stream>>>(B, Bt);
        gemm_bf16_256<<<(M_DIM / BM) * (H_DIM / BN), 512, 0, stream>>>(xb, Bt, out);
    } else {
        gemm_fp32_fallback<<<(M_DIM / 64) * (H_DIM / 64), 256, 0, stream>>>(x, B, out);
    }
    scan_kernel<<<BATCH_, 512, 0, stream>>>(h0, dd, L, R, out);
}

// Round 3
// 392.252 us; speedup vs baseline: 1.1195x; 1.1195x over previous
//
#include <hip/hip_runtime.h>
#include <hip/hip_bf16.h>

#define H_DIM  1024
#define RANK_  4
#define BATCH_ 128
#define TSTEPS 256
#define M_DIM  (BATCH_ * TSTEPS)   // 32768

typedef __bf16 bf16x8 __attribute__((ext_vector_type(8)));
typedef float  floatx4 __attribute__((ext_vector_type(4)));
typedef unsigned short ushortx8 __attribute__((ext_vector_type(8)));

// RNE float -> bf16 (branchless; inputs are finite)
__device__ __forceinline__ unsigned short f2bf(float f) {
    unsigned u = __float_as_uint(f);
    u += 0x7FFFu + ((u >> 16) & 1u);
    return (unsigned short)(u >> 16);
}

// ---------------- fused conversion kernel ----------------
// blocks [0, NXB): x fp32 -> bf16 (vectorized 8/lane)
// blocks [NXB, NXB+1024): Bt[n][k] = bf16(B[k][n]) 32x32 tiles
#define NXB ((M_DIM * H_DIM) / (256 * 8))   // 16384

__global__ __launch_bounds__(256) void cvt_fused_kernel(const float* __restrict__ x,
                                                        unsigned short* __restrict__ xb,
                                                        const float* __restrict__ B,
                                                        unsigned short* __restrict__ Bt) {
    __shared__ float tl[32][33];
    const int bid = blockIdx.x;
    if (bid < NXB) {
        size_t i = ((size_t)bid * 256 + threadIdx.x) * 8;
        float4 v0 = *(const float4*)(x + i);
        float4 v1 = *(const float4*)(x + i + 4);
        ushortx8 o;
        o[0] = f2bf(v0.x); o[1] = f2bf(v0.y); o[2] = f2bf(v0.z); o[3] = f2bf(v0.w);
        o[4] = f2bf(v1.x); o[5] = f2bf(v1.y); o[6] = f2bf(v1.z); o[7] = f2bf(v1.w);
        *(ushortx8*)(xb + i) = o;
    } else {
        const int t = bid - NXB;               // 0..1023
        int tx = threadIdx.x & 31, ty = threadIdx.x >> 5;   // ty in 0..7
        int k0 = (t >> 5) * 32, n0 = (t & 31) * 32;
#pragma unroll
        for (int j = 0; j < 4; ++j)
            tl[ty + 8 * j][tx] = B[(size_t)(k0 + ty + 8 * j) * H_DIM + n0 + tx];
        __syncthreads();
#pragma unroll
        for (int j = 0; j < 4; ++j)
            Bt[(size_t)(n0 + ty + 8 * j) * H_DIM + k0 + tx] = f2bf(tl[tx][ty + 8 * j]);
    }
}

// ---------------- bf16 MFMA GEMM, 256x256 8-phase schedule ----------------
// (unchanged: dropped from 147us to below the scan on the dispatch table)

#define BM 256
#define BN 256
#define BKK 64
#define KTILES (H_DIM / BKK)   // 16

#define GLD(srcptr, dstptr)                                          \
    __builtin_amdgcn_global_load_lds(                                \
        (const __attribute__((address_space(1))) void*)(srcptr),     \
        (__attribute__((address_space(3))) void*)(dstptr), 16, 0, 0)

#define STAGE_A(buf, hf, kt) do {                                                     \
    GLD(aS0 + (size_t)(hf) * (128 * H_DIM) + (kt) * BKK, &lds[buf][0][hf][dst0]);     \
    GLD(aS1 + (size_t)(hf) * (128 * H_DIM) + (kt) * BKK, &lds[buf][0][hf][dst1]);     \
} while (0)

#define STAGE_B(buf, hf, kt) do {                                                     \
    GLD(bS0 + (size_t)(hf) * (128 * H_DIM) + (kt) * BKK, &lds[buf][1][hf][dst0]);     \
    GLD(bS1 + (size_t)(hf) * (128 * H_DIM) + (kt) * BKK, &lds[buf][1][hf][dst1]);     \
} while (0)

#define MFMA_PHASE(q)                                                                                         \
    _Pragma("unroll")                                                                                         \
    for (int fc = 0; fc < 4; ++fc) {                                                                          \
        acc[2*(q)][fc]   = __builtin_amdgcn_mfma_f32_16x16x32_bf16(a00, bfr[fc][0], acc[2*(q)][fc], 0, 0, 0);   \
        acc[2*(q)][fc]   = __builtin_amdgcn_mfma_f32_16x16x32_bf16(a01, bfr[fc][1], acc[2*(q)][fc], 0, 0, 0);   \
        acc[2*(q)+1][fc] = __builtin_amdgcn_mfma_f32_16x16x32_bf16(a10, bfr[fc][0], acc[2*(q)+1][fc], 0, 0, 0); \
        acc[2*(q)+1][fc] = __builtin_amdgcn_mfma_f32_16x16x32_bf16(a11, bfr[fc][1], acc[2*(q)+1][fc], 0, 0, 0); \
    }

#define PHASE(q, STAGE_STMT, TAIL_STMT) {                                      \
        bf16x8 a00 = *(const bf16x8*)(Ah + (2*(q))     * 1024 + aRow + cs0);   \
        bf16x8 a01 = *(const bf16x8*)(Ah + (2*(q))     * 1024 + aRow + cs1);   \
        bf16x8 a10 = *(const bf16x8*)(Ah + (2*(q) + 1) * 1024 + aRow + cs0);   \
        bf16x8 a11 = *(const bf16x8*)(Ah + (2*(q) + 1) * 1024 + aRow + cs1);   \
        STAGE_STMT;                                                            \
        __builtin_amdgcn_s_barrier();                                          \
        asm volatile("s_waitcnt lgkmcnt(0)" ::: "memory");                     \
        __builtin_amdgcn_s_setprio(1);                                         \
        MFMA_PHASE(q);                                                         \
        __builtin_amdgcn_s_setprio(0);                                         \
        TAIL_STMT;                                                             \
        __builtin_amdgcn_s_barrier();                                          \
    }

__global__ __launch_bounds__(512, 2) void gemm_bf16_256(const unsigned short* __restrict__ A,
                                                        const unsigned short* __restrict__ Bt,
                                                        float* __restrict__ C) {
    __shared__ unsigned short lds[2][2][2][8192];   // [dbuf][A=0/B=1][half][128*64] = 128KB

    const int tid = threadIdx.x;
    const int l   = tid & 63;
    const int w   = tid >> 6;      // 0..7
    const int wr  = w >> 2;        // 0..1  M-side (128 rows)
    const int wc  = w & 3;         // 0..3  N-side (64 cols)

    const int bid = blockIdx.x;
    const int lt  = (bid & 7) * 64 + (bid >> 3);
    const int m0  = (lt >> 2) * BM;
    const int n0  = (lt & 3)  * BN;

    const int p0row = (w * 2 + 0) * 8 + (l >> 3);
    const int p1row = (w * 2 + 1) * 8 + (l >> 3);
    const int gcol  = ((l & 7) ^ (l >> 3)) * 8;
    const int dst0  = (w * 2 + 0) * 512;
    const int dst1  = (w * 2 + 1) * 512;
    const unsigned short* aS0 = A  + (size_t)(m0 + p0row) * H_DIM + gcol;
    const unsigned short* aS1 = A  + (size_t)(m0 + p1row) * H_DIM + gcol;
    const unsigned short* bS0 = Bt + (size_t)(n0 + p0row) * H_DIM + gcol;
    const unsigned short* bS1 = Bt + (size_t)(n0 + p1row) * H_DIM + gcol;

    const int aRow = (l & 15) * 64;
    const int cs0  = (((l >> 4) + 0) ^ (l & 7)) * 8;
    const int cs1  = (((l >> 4) + 4) ^ (l & 7)) * 8;

    floatx4 acc[8][4];
#pragma unroll
    for (int i = 0; i < 8; ++i)
#pragma unroll
        for (int j = 0; j < 4; ++j) acc[i][j] = (floatx4){0.f, 0.f, 0.f, 0.f};

    STAGE_B(0, 0, 0); STAGE_B(0, 1, 0); STAGE_A(0, 0, 0); STAGE_A(0, 1, 0);
    STAGE_B(1, 0, 1); STAGE_B(1, 1, 1); STAGE_A(1, 0, 1);
    asm volatile("s_waitcnt vmcnt(6)" ::: "memory");   // oldest 4 halves (t0) done
    __builtin_amdgcn_s_barrier();

    for (int kt = 0; kt < KTILES; ++kt) {
        const int buf = kt & 1;
        const unsigned short* Ah = &lds[buf][0][wr][0];
        const unsigned short* Bh = &lds[buf][1][wc >> 1][(wc & 1) * 4096];
        bf16x8 bfr[4][2];

        {
            bf16x8 a00 = *(const bf16x8*)(Ah + 0 * 1024 + aRow + cs0);
            bf16x8 a01 = *(const bf16x8*)(Ah + 0 * 1024 + aRow + cs1);
            bf16x8 a10 = *(const bf16x8*)(Ah + 1 * 1024 + aRow + cs0);
            bf16x8 a11 = *(const bf16x8*)(Ah + 1 * 1024 + aRow + cs1);
#pragma unroll
            for (int fc = 0; fc < 4; ++fc) {
                bfr[fc][0] = *(const bf16x8*)(Bh + fc * 1024 + aRow + cs0);
                bfr[fc][1] = *(const bf16x8*)(Bh + fc * 1024 + aRow + cs1);
            }
            if (kt + 1 < KTILES) STAGE_A(buf ^ 1, 1, kt + 1);
            __builtin_amdgcn_s_barrier();
            asm volatile("s_waitcnt lgkmcnt(0)" ::: "memory");
            __builtin_amdgcn_s_setprio(1);
            MFMA_PHASE(0);
            __builtin_amdgcn_s_setprio(0);
            __builtin_amdgcn_s_barrier();
        }
        PHASE(1, if (kt + 2 < KTILES) STAGE_B(buf, 0, kt + 2), );
        PHASE(2, if (kt + 2 < KTILES) STAGE_B(buf, 1, kt + 2), );
        PHASE(3, if (kt + 2 < KTILES) STAGE_A(buf, 0, kt + 2),
              if (kt < KTILES - 2) { asm volatile("s_waitcnt vmcnt(6)" ::: "memory"); }
              else if (kt == KTILES - 2) { asm volatile("s_waitcnt vmcnt(0)" ::: "memory"); });
    }

    const int cr = (l >> 4) * 4;
    const int cc = l & 15;
#pragma unroll
    for (int fr = 0; fr < 8; ++fr)
#pragma unroll
        for (int fc = 0; fc < 4; ++fc) {
            size_t base = (size_t)(m0 + wr * 128 + fr * 16 + cr) * H_DIM
                        + (n0 + wc * 64 + fc * 16 + cc);
#pragma unroll
            for (int r = 0; r < 4; ++r)
                C[base + (size_t)r * H_DIM] = acc[fr][fc][r];
        }
}

// ---------------- fp32 fallback GEMM (only if ws too small) ----------------
__global__ __launch_bounds__(256) void gemm_fp32_fallback(const float* __restrict__ A,
                                                          const float* __restrict__ B,
                                                          float* __restrict__ C) {
    __shared__ float As[64][20];
    __shared__ float Bs[16][68];
    const int tid = threadIdx.x;
    const int bm = blockIdx.x >> 4, bn = blockIdx.x & 15;
    const int m0 = bm * 64, n0 = bn * 64;
    const int tx = (tid & 15) * 4, ty = (tid >> 4) * 4;
    float acc[4][4];
#pragma unroll
    for (int i = 0; i < 4; ++i)
#pragma unroll
        for (int j = 0; j < 4; ++j) acc[i][j] = 0.f;

    for (int kk = 0; kk < H_DIM; kk += 16) {
        float4 av = *(const float4*)(A + (size_t)(m0 + (tid >> 2)) * H_DIM + kk + (tid & 3) * 4);
        float4 bv = *(const float4*)(B + (size_t)(kk + (tid >> 4)) * H_DIM + n0 + (tid & 15) * 4);
        __syncthreads();
        *(float4*)&As[tid >> 2][(tid & 3) * 4] = av;
        *(float4*)&Bs[tid >> 4][(tid & 15) * 4] = bv;
        __syncthreads();
#pragma unroll
        for (int k = 0; k < 16; ++k) {
            float a_[4], b_[4];
#pragma unroll
            for (int i = 0; i < 4; ++i) a_[i] = As[ty + i][k];
#pragma unroll
            for (int j = 0; j < 4; ++j) b_[j] = Bs[k][tx + j];
#pragma unroll
            for (int i = 0; i < 4; ++i)
#pragma unroll
                for (int j = 0; j < 4; ++j) acc[i][j] += a_[i] * b_[j];
        }
    }
#pragma unroll
    for (int i = 0; i < 4; ++i)
#pragma unroll
        for (int j = 0; j < 4; ++j)
            C[(size_t)(m0 + ty + i) * H_DIM + n0 + tx + j] = acc[i][j];
}

// ---------------- sequential scan (in-place on d_out) ----------------
// REVERTED to the 4-wave x 4-el/lane structure (108.8us measured); the 8-wave
// variant regressed to 155us (deeper post-barrier combine + 2 waves/SIMD
// serializing issue). Kept from the experiment: a = d*h + u hoisted BEFORE the
// barrier (independent of r -> fills exchange latency).

__device__ __forceinline__ float tanh_fast(float x) {
    float ax = fabsf(x);
    float e  = __expf(-2.0f * ax);
    float t  = (1.0f - e) * __builtin_amdgcn_rcpf(1.0f + e);
    return copysignf(t, x);
}

// LDS-only barrier: drains lgkmcnt but NOT vmcnt, so global prefetch loads
// and h-stores stay in flight across the barrier.
__device__ __forceinline__ void barrier_lds_only() {
    asm volatile("s_waitcnt lgkmcnt(0)\n\ts_barrier" ::: "memory");
}

// DPP wave64 sum: full sum lands in lane 63 (VALU-rate, no LDS/ds_permute).
template <int CTRL, int RMASK>
__device__ __forceinline__ float dpp_add(float x) {
    int v = __builtin_amdgcn_update_dpp(0, __float_as_int(x), CTRL, RMASK, 0xf, true);
    return x + __int_as_float(v);
}
__device__ __forceinline__ float wave_sum64(float x) {
    x = dpp_add<0x111, 0xf>(x);  // row_shr:1
    x = dpp_add<0x112, 0xf>(x);  // row_shr:2
    x = dpp_add<0x114, 0xf>(x);  // row_shr:4
    x = dpp_add<0x118, 0xf>(x);  // row_shr:8  -> lane15 of each row = row sum
    x = dpp_add<0x142, 0xa>(x);  // row_bcast15 -> rows 1,3
    x = dpp_add<0x143, 0xc>(x);  // row_bcast31 -> rows 2,3; lane 63 = total
    return x;
}

__global__ __launch_bounds__(256) void scan_kernel(const float* __restrict__ h0,
                                                   const float* __restrict__ d,
                                                   const float* __restrict__ Lm,
                                                   const float* __restrict__ Rm,
                                                   float* __restrict__ io) {
    const int b = blockIdx.x, tid = threadIdx.x;
    const int lane = tid & 63, wv = tid >> 6;
    const int e = tid * 4;

    float4 dv4 = *(const float4*)(d + e);
    float dd[4] = {dv4.x, dv4.y, dv4.z, dv4.w};
    float4 hv4 = *(const float4*)(h0 + (size_t)b * H_DIM + e);
    float h[4] = {hv4.x, hv4.y, hv4.z, hv4.w};

    float Lv[4][4], Rv[4][4];
#pragma unroll
    for (int i = 0; i < 4; ++i) {
        float4 t = *(const float4*)(Lm + (size_t)(e + i) * RANK_);   // L[h][j]
        Lv[i][0] = t.x; Lv[i][1] = t.y; Lv[i][2] = t.z; Lv[i][3] = t.w;
    }
#pragma unroll
    for (int j = 0; j < 4; ++j) {
        float4 t = *(const float4*)(Rm + (size_t)j * H_DIM + e);     // R[j][h]
        Rv[j][0] = t.x; Rv[j][1] = t.y; Rv[j][2] = t.z; Rv[j][3] = t.w;
    }

    float* iob = io + (size_t)b * TSTEPS * H_DIM + e;
    __shared__ float red[2][4][4];   // double-buffered: 1 barrier/step is sound

    // prefetch distance 4, circular buffer, loop unrolled by 4 (static index)
    float4 u[4];
#pragma unroll
    for (int s = 0; s < 4; ++s) u[s] = *(const float4*)(iob + (size_t)s * H_DIM);

    for (int t = 0; t < TSTEPS; t += 4) {
#pragma unroll
        for (int s = 0; s < 4; ++s) {
            const int tt = t + s;
            float pr[4];
#pragma unroll
            for (int j = 0; j < 4; ++j)
                pr[j] = Rv[j][0] * h[0] + Rv[j][1] * h[1] + Rv[j][2] * h[2] + Rv[j][3] * h[3];
#pragma unroll
            for (int j = 0; j < 4; ++j) pr[j] = wave_sum64(pr[j]);
            if (lane == 63) {
                float4 w; w.x = pr[0]; w.y = pr[1]; w.z = pr[2]; w.w = pr[3];
                *(float4*)&red[s & 1][wv][0] = w;
            }
            // a = d*h + u is independent of r: compute before the barrier so it
            // overlaps the exchange latency.
            float a_[4];
#pragma unroll
            for (int i = 0; i < 4; ++i) a_[i] = fmaf(dd[i], h[i], (&u[s].x)[i]);
            barrier_lds_only();
            float4 r0 = *(const float4*)&red[s & 1][0][0];
            float4 r1 = *(const float4*)&red[s & 1][1][0];
            float4 r2 = *(const float4*)&red[s & 1][2][0];
            float4 r3 = *(const float4*)&red[s & 1][3][0];
            float r[4] = {r0.x + r1.x + r2.x + r3.x, r0.y + r1.y + r2.y + r3.y,
                          r0.z + r1.z + r2.z + r3.z, r0.w + r1.w + r2.w + r3.w};

#pragma unroll
            for (int i = 0; i < 4; ++i) {
                float a = a_[i] + Lv[i][0] * r[0] + Lv[i][1] * r[1]
                                + Lv[i][2] * r[2] + Lv[i][3] * r[3];
                h[i] = tanh_fast(a);
            }
            float4 o; o.x = h[0]; o.y = h[1]; o.z = h[2]; o.w = h[3];
            *(float4*)(iob + (size_t)tt * H_DIM) = o;
            if (tt + 4 < TSTEPS) u[s] = *(const float4*)(iob + (size_t)(tt + 4) * H_DIM);
        }
    }
}

// ---------------- launch ----------------

extern "C" void kernel_launch(void* const* d_in, const int* in_sizes, int n_in,
                              void* d_out, int out_size, void* d_ws, size_t ws_size,
                              hipStream_t stream) {
    const float* x  = (const float*)d_in[0];
    const float* h0 = (const float*)d_in[1];
    const float* dd = (const float*)d_in[2];
    const float* L  = (const float*)d_in[3];
    const float* R  = (const float*)d_in[4];
    const float* B  = (const float*)d_in[5];
    float* out = (float*)d_out;

    const size_t need = (size_t)M_DIM * H_DIM * sizeof(unsigned short)
                      + (size_t)H_DIM * H_DIM * sizeof(unsigned short);
    if (ws_size >= need) {
        unsigned short* xb = (unsigned short*)d_ws;
        unsigned short* Bt = xb + (size_t)M_DIM * H_DIM;
        cvt_fused_kernel<<<NXB + 1024, 256, 0, stream>>>(x, xb, B, Bt);
        gemm_bf16_256<<<(M_DIM / BM) * (H_DIM / BN), 512, 0, stream>>>(xb, Bt, out);
    } else {
        gemm_fp32_fallback<<<(M_DIM / 64) * (H_DIM / 64), 256, 0, stream>>>(x, B, out);
    }
    scan_kernel<<<BATCH_, 256, 0, stream>>>(h0, dd, L, R, out);
}